// Round 21
// baseline (39.168 us; speedup 1.0000x reference)
//
#include <hip/hip_runtime.h>

#define OUT_DIM 4096
#define IN_DIM 4096
#define NNZ 327680
#define BNNZ 2048
#define BATCH 512
#define NCHK 64            // CSR chunks (one block each)
#define CNNZ (NNZ / NCHK)  // 5120 nnz per chunk
#define SMAX 160           // spmm staging cap (max row cnt ~118; P(>160)~1e-15)
#define RT 8               // rows per spmm block (2 waves per row)
#define TT 512             // transpose blocks (4 tiles each)

typedef int   i2 __attribute__((ext_vector_type(2)));
typedef float f4 __attribute__((ext_vector_type(4)));

// fp32 -> bf16 round-to-nearest-even
__device__ __forceinline__ unsigned short f2bf(float f) {
    unsigned int x = __float_as_uint(f);
    x += 0x7fffu + ((x >> 16) & 1u);
    return (unsigned short)(x >> 16);
}

// prep LDS: CSR branch 60.1 KB, transpose branch 16.9 KB -> union
union PrepSMem {
    struct { float tile[4][32][33]; } a;
    struct { int h[OUT_DIM]; int ws[16]; int2 sl[CNNZ]; } b;
};

// ---- prep: block-specialized {chunk-local CSR build} U {transpose} --------
// CSR blocks first (long pole). Scan is now wave-shfl based: 2 barriers
// instead of 20 (Hillis-Steele) — shaves the CSR critical path.
__global__ __launch_bounds__(1024)
void prep_k(const float* __restrict__ in, unsigned short* __restrict__ inputT,
            const int* __restrict__ rows, const int* __restrict__ cols,
            const float* __restrict__ vals,
            int* __restrict__ lrp, int2* __restrict__ slots) {
    __shared__ PrepSMem u;
    const int bid = blockIdx.x, t = threadIdx.x;
    if (bid >= NCHK) {
        const int g = t >> 8, tx = t & 31, ty = (t >> 5) & 7;
        const int job = (bid - NCHK) * 4 + g;   // 0..2047
        const int bx = (job & 127) << 5;        // IN tile origin
        const int by = (job >> 7) << 5;         // B tile origin
        for (int i = ty; i < 32; i += 8)
            u.a.tile[g][i][tx] = in[(size_t)(by + i) * IN_DIM + bx + tx];
        __syncthreads();
        for (int i = ty; i < 32; i += 8)
            inputT[(size_t)(bx + i) * BATCH + by + tx] = f2bf(u.a.tile[g][tx][i]);
    } else {
        const int c = bid;
        const int base = c * CNNZ;
        const int lane = t & 63, wv = t >> 6;
#pragma unroll
        for (int i = 0; i < 4; ++i) u.b.h[i * 1024 + t] = 0;
        __syncthreads();
#pragma unroll
        for (int i = 0; i < CNNZ / 1024; ++i)
            atomicAdd(&u.b.h[rows[base + i * 1024 + t]], 1);  // LDS atomic
        __syncthreads();
        const int c0 = u.b.h[4 * t], c1 = u.b.h[4 * t + 1];
        const int c2 = u.b.h[4 * t + 2], c3 = u.b.h[4 * t + 3];
        const int sum = c0 + c1 + c2 + c3;
        // wave-level inclusive scan of sum (no barriers)
        int x = sum;
#pragma unroll
        for (int d = 1; d < 64; d <<= 1) {
            const int y = __shfl_up(x, d, 64);
            if (lane >= d) x += y;
        }
        if (lane == 63) u.b.ws[wv] = x;
        __syncthreads();
        if (t < 16) {                       // scan the 16 wave totals
            const int v = u.b.ws[t];
            int xx = v;
#pragma unroll
            for (int d = 1; d < 16; d <<= 1) {
                const int y = __shfl_up(xx, d, 64);
                if (t >= d) xx += y;
            }
            u.b.ws[t] = xx - v;             // exclusive wave base
        }
        __syncthreads();
        const int e0 = u.b.ws[wv] + (x - sum);
        const int e1 = e0 + c0, e2 = e1 + c1, e3 = e2 + c2;
        u.b.h[4 * t] = e0; u.b.h[4 * t + 1] = e1;
        u.b.h[4 * t + 2] = e2; u.b.h[4 * t + 3] = e3;
        int* lc = lrp + (size_t)c * 4097;
        lc[4 * t] = e0; lc[4 * t + 1] = e1; lc[4 * t + 2] = e2; lc[4 * t + 3] = e3;
        if (t == 1023) lc[4096] = CNNZ;
        __syncthreads();
#pragma unroll
        for (int i = 0; i < CNNZ / 1024; ++i) {
            const int k = base + i * 1024 + t;
            const int r = rows[k];
            const int p = atomicAdd(&u.b.h[r], 1);            // LDS cursor
            u.b.sl[p] = make_int2(cols[k] * (BATCH * 2),      // LDS scatter
                                  __float_as_int(vals[k]));
        }
        __syncthreads();
#pragma unroll
        for (int i = 0; i < CNNZ / 1024; ++i)                 // coalesced out
            slots[base + i * 1024 + t] = u.b.sl[i * 1024 + t];
    }
}

// --- SpMM: TWO waves per row (each owns half the slot list), full-width
// --- dwordx4 gathers. 8 rows x 1024 thr, LDS 26KB, launch_bounds(1024,8)
// --- -> 2 blocks/CU = 32 waves/CU (r6 had 16): the clean occupancy probe
// --- r14 confounded by halving gather width. Per-CU outstanding gathers 2x.
__global__ __launch_bounds__(1024, 8)
void spmm_k(const unsigned short* __restrict__ inputT, const int* __restrict__ lrp,
            const int2* __restrict__ slots, const int* __restrict__ b_idx,
            const float* __restrict__ b_vals, float* __restrict__ out) {
    const int w = threadIdx.x >> 6;      // wave id 0..15
    const int h = w & 1;                 // half index within row pair
    const int w2 = w >> 1;               // row within block 0..7
    const int lane = threadIdx.x & 63;
    const int r0 = blockIdx.x * RT;
    const int r = r0 + w2;

    __shared__ int2  s_slot[RT][SMAX];   // 10 KB
    __shared__ float tile[RT][BATCH];    // 16 KB
    __shared__ float bias_l[RT];

    if (threadIdx.x < RT) bias_l[threadIdx.x] = 0.f;
    __syncthreads();

    // ---- 64-segment staging (both waves of a pair scan; copy own half) ----
    const int* lc = lrp + (size_t)lane * 4097;
    const int beg = lc[r];
    const int cnt = lc[r + 1] - beg;
    int x = cnt;
#pragma unroll
    for (int d = 1; d < 64; d <<= 1) {
        const int y = __shfl_up(x, d, 64);
        if (lane >= d) x += y;
    }
    const int excl = x - cnt;
    int total = __shfl(x, 63, 64);
    total = min(total, SMAX);
    const int halfc = total >> 1;
    const int jbeg = h ? halfc : 0;
    const int jend = h ? total : halfc;
    for (int j = 0; j < cnt; ++j) {
        const int p = excl + j;
        if (p >= jbeg && p < jend) {
            i2 sv = __builtin_nontemporal_load(
                reinterpret_cast<const i2*>(&slots[lane * CNNZ + beg + j]));
            s_slot[w2][p] = make_int2(sv.x, sv.y);
        }
    }

    // ---- sparse bias -> bias_l (2 entries per thread, coalesced) ----
#pragma unroll
    for (int i = 0; i < 2; ++i) {
        const int ii = threadIdx.x * 2 + i;
        const int d = b_idx[ii] - r0;
        if ((unsigned)d < RT) atomicAdd(&bias_l[d], b_vals[ii]);
    }

    // ---- gather + FMA over this wave's half (reads only what it staged) ----
    const char* base = (const char*)inputT + lane * 16;
    float a0 = 0.f, a1 = 0.f, a2 = 0.f, a3 = 0.f;
    float a4 = 0.f, a5 = 0.f, a6 = 0.f, a7 = 0.f;
#pragma unroll 4
    for (int j = jbeg; j < jend; ++j) {
        const int2 sv = s_slot[w2][j];
        const uint4 q = *reinterpret_cast<const uint4*>(base + sv.x);
        const float v = __int_as_float(sv.y);
        a0 = fmaf(v, __uint_as_float(q.x << 16), a0);
        a1 = fmaf(v, __uint_as_float(q.x & 0xffff0000u), a1);
        a2 = fmaf(v, __uint_as_float(q.y << 16), a2);
        a3 = fmaf(v, __uint_as_float(q.y & 0xffff0000u), a3);
        a4 = fmaf(v, __uint_as_float(q.z << 16), a4);
        a5 = fmaf(v, __uint_as_float(q.z & 0xffff0000u), a5);
        a6 = fmaf(v, __uint_as_float(q.w << 16), a6);
        a7 = fmaf(v, __uint_as_float(q.w & 0xffff0000u), a7);
    }
    // ---- merge the two halves: h=0 writes, h=1 adds ----
    float* tp = &tile[w2][lane * 8];
    if (h == 0) {
        tp[0] = a0; tp[1] = a1; tp[2] = a2; tp[3] = a3;
        tp[4] = a4; tp[5] = a5; tp[6] = a6; tp[7] = a7;
    }
    __syncthreads();
    if (h == 1) {
        tp[0] += a0; tp[1] += a1; tp[2] += a2; tp[3] += a3;
        tp[4] += a4; tp[5] += a5; tp[6] += a6; tp[7] += a7;
    }
    __syncthreads();

    // store: thread t -> bl = t/2, r-quad = (t&1)*4; float4 along r (32B per
    // thread pair; cached stores merge in L2 — nt on partial lines regressed r9)
    const int rq = (threadIdx.x & 1) * 4;
    const int bl = threadIdx.x >> 1;     // 0..511
    const float4 bv = make_float4(bias_l[rq + 0], bias_l[rq + 1],
                                  bias_l[rq + 2], bias_l[rq + 3]);
    float4 o = make_float4(tile[rq + 0][bl] + bv.x, tile[rq + 1][bl] + bv.y,
                           tile[rq + 2][bl] + bv.z, tile[rq + 3][bl] + bv.w);
    *reinterpret_cast<float4*>(&out[(size_t)bl * OUT_DIM + r0 + rq]) = o;
}

extern "C" void kernel_launch(void* const* d_in, const int* in_sizes, int n_in,
                              void* d_out, int out_size, void* d_ws, size_t ws_size,
                              hipStream_t stream) {
    const float* input   = (const float*)d_in[0];
    const int*   w_rows  = (const int*)d_in[1];
    const int*   w_cols  = (const int*)d_in[2];
    const float* w_vals  = (const float*)d_in[3];
    const int*   b_idx   = (const int*)d_in[4];
    const float* b_vals  = (const float*)d_in[5];
    float* out = (float*)d_out;

    char* ws = (char*)d_ws;
    const size_t MB = (size_t)1024 * 1024;
    unsigned short* inputT = (unsigned short*)ws;      // 4 MiB (bf16)
    int*   lrp   = (int*)(ws + 4 * MB);                // 64*4097*4 ~= 1.0 MiB
    int2*  slots = (int2*)(ws + 6 * MB);               // NNZ*8 = 2.56 MiB

    prep_k<<<NCHK + TT, 1024, 0, stream>>>(input, inputT, w_rows, w_cols, w_vals,
                                           lrp, slots);

    spmm_k<<<OUT_DIM / RT, 1024, 0, stream>>>(inputT, lrp, slots, b_idx, b_vals,
                                              out);
}

// Round 22
// 36.915 us; speedup vs baseline: 1.0610x; 1.0610x over previous
//
#include <hip/hip_runtime.h>

#define OUT_DIM 4096
#define IN_DIM 4096
#define NNZ 327680
#define BNNZ 2048
#define BATCH 512
#define NCHK 64            // CSR chunks (one block each)
#define CNNZ (NNZ / NCHK)  // 5120 nnz per chunk
#define SMAX 160           // spmm staging cap (max row cnt ~118; P(>160)~1e-15)
#define RT 16              // rows per spmm block
#define TT 512             // transpose blocks (4 tiles each)

typedef int   i2 __attribute__((ext_vector_type(2)));
typedef float f4 __attribute__((ext_vector_type(4)));

// fp32 -> bf16 round-to-nearest-even
__device__ __forceinline__ unsigned short f2bf(float f) {
    unsigned int x = __float_as_uint(f);
    x += 0x7fffu + ((x >> 16) & 1u);
    return (unsigned short)(x >> 16);
}

// prep LDS: CSR branch 60.1 KB, transpose branch 16.9 KB -> union
union PrepSMem {
    struct { float tile[4][32][33]; } a;
    struct { int h[OUT_DIM]; int ws[16]; int2 sl[CNNZ]; } b;
};

// ---- prep: block-specialized {chunk-local CSR build} U {transpose} --------
// CSR blocks first (long pole). Wave-shfl scan (2 barriers, r21's separable
// win). LDS scatter + coalesced copy-out (r20's win: no random global stores).
__global__ __launch_bounds__(1024)
void prep_k(const float* __restrict__ in, unsigned short* __restrict__ inputT,
            const int* __restrict__ rows, const int* __restrict__ cols,
            const float* __restrict__ vals,
            int* __restrict__ lrp, int2* __restrict__ slots) {
    __shared__ PrepSMem u;
    const int bid = blockIdx.x, t = threadIdx.x;
    if (bid >= NCHK) {
        const int g = t >> 8, tx = t & 31, ty = (t >> 5) & 7;
        const int job = (bid - NCHK) * 4 + g;   // 0..2047
        const int bx = (job & 127) << 5;        // IN tile origin
        const int by = (job >> 7) << 5;         // B tile origin
        for (int i = ty; i < 32; i += 8)
            u.a.tile[g][i][tx] = in[(size_t)(by + i) * IN_DIM + bx + tx];
        __syncthreads();
        for (int i = ty; i < 32; i += 8)
            inputT[(size_t)(bx + i) * BATCH + by + tx] = f2bf(u.a.tile[g][tx][i]);
    } else {
        const int c = bid;
        const int base = c * CNNZ;
        const int lane = t & 63, wv = t >> 6;
#pragma unroll
        for (int i = 0; i < 4; ++i) u.b.h[i * 1024 + t] = 0;
        __syncthreads();
#pragma unroll
        for (int i = 0; i < CNNZ / 1024; ++i)
            atomicAdd(&u.b.h[rows[base + i * 1024 + t]], 1);  // LDS atomic
        __syncthreads();
        const int c0 = u.b.h[4 * t], c1 = u.b.h[4 * t + 1];
        const int c2 = u.b.h[4 * t + 2], c3 = u.b.h[4 * t + 3];
        const int sum = c0 + c1 + c2 + c3;
        // wave-level inclusive scan of sum (no barriers)
        int x = sum;
#pragma unroll
        for (int d = 1; d < 64; d <<= 1) {
            const int y = __shfl_up(x, d, 64);
            if (lane >= d) x += y;
        }
        if (lane == 63) u.b.ws[wv] = x;
        __syncthreads();
        if (t < 16) {                       // scan the 16 wave totals
            const int v = u.b.ws[t];
            int xx = v;
#pragma unroll
            for (int d = 1; d < 16; d <<= 1) {
                const int y = __shfl_up(xx, d, 64);
                if (t >= d) xx += y;
            }
            u.b.ws[t] = xx - v;             // exclusive wave base
        }
        __syncthreads();
        const int e0 = u.b.ws[wv] + (x - sum);
        const int e1 = e0 + c0, e2 = e1 + c1, e3 = e2 + c2;
        u.b.h[4 * t] = e0; u.b.h[4 * t + 1] = e1;
        u.b.h[4 * t + 2] = e2; u.b.h[4 * t + 3] = e3;
        int* lc = lrp + (size_t)c * 4097;
        lc[4 * t] = e0; lc[4 * t + 1] = e1; lc[4 * t + 2] = e2; lc[4 * t + 3] = e3;
        if (t == 1023) lc[4096] = CNNZ;
        __syncthreads();
#pragma unroll
        for (int i = 0; i < CNNZ / 1024; ++i) {
            const int k = base + i * 1024 + t;
            const int r = rows[k];
            const int p = atomicAdd(&u.b.h[r], 1);            // LDS cursor
            u.b.sl[p] = make_int2(cols[k] * (BATCH * 2),      // LDS scatter
                                  __float_as_int(vals[k]));
        }
        __syncthreads();
#pragma unroll
        for (int i = 0; i < CNNZ / 1024; ++i)                 // coalesced out
            slots[base + i * 1024 + t] = u.b.sl[i * 1024 + t];
    }
}

// --- SpMM: r20's exact kernel (best known ~30us; at the per-CU line-visit
// --- floor — survived MLP r10, nt r11/r19, occupancy r14/r21, LDS-slab r12).
__global__ __launch_bounds__(1024, 4)
void spmm_k(const unsigned short* __restrict__ inputT, const int* __restrict__ lrp,
            const int2* __restrict__ slots, const int* __restrict__ b_idx,
            const float* __restrict__ b_vals, float* __restrict__ out) {
    const int w = threadIdx.x >> 6;      // wave = row within block
    const int lane = threadIdx.x & 63;   // lane = chunk (staging) / 8 b (gather)
    const int r0 = blockIdx.x * RT;
    const int r = r0 + w;

    __shared__ int2  s_slot[RT][SMAX];   // 20 KB, wave-private rows
    __shared__ float tile[RT][BATCH];    // 32 KB
    __shared__ float bias_l[RT];

    if (threadIdx.x < RT) bias_l[threadIdx.x] = 0.f;
    __syncthreads();

    // ---- 64-segment staging (slot loads nt: read exactly once) ----
    const int* lc = lrp + (size_t)lane * 4097;
    const int beg = lc[r];
    const int cnt = lc[r + 1] - beg;
    int x = cnt;
#pragma unroll
    for (int d = 1; d < 64; d <<= 1) {
        const int y = __shfl_up(x, d, 64);
        if (lane >= d) x += y;
    }
    const int excl = x - cnt;
    int total = __shfl(x, 63, 64);
    total = min(total, SMAX);
    for (int j = 0; j < cnt; ++j) {
        const int p = excl + j;
        if (p < SMAX) {
            i2 sv = __builtin_nontemporal_load(
                reinterpret_cast<const i2*>(&slots[lane * CNNZ + beg + j]));
            s_slot[w][p] = make_int2(sv.x, sv.y);
        }
    }

    // ---- sparse bias -> bias_l (2 entries per thread, coalesced) ----
#pragma unroll
    for (int i = 0; i < 2; ++i) {
        const int ii = threadIdx.x * 2 + i;
        const int d = b_idx[ii] - r0;
        if ((unsigned)d < RT) atomicAdd(&bias_l[d], b_vals[ii]);
    }

    // ---- gather + FMA (cached loads) ----
    const char* base = (const char*)inputT + lane * 16;
    float a0 = 0.f, a1 = 0.f, a2 = 0.f, a3 = 0.f;
    float a4 = 0.f, a5 = 0.f, a6 = 0.f, a7 = 0.f;
#pragma unroll 4
    for (int j = 0; j < total; ++j) {
        const int2 sv = s_slot[w][j];
        const uint4 q = *reinterpret_cast<const uint4*>(base + sv.x);
        const float v = __int_as_float(sv.y);
        a0 = fmaf(v, __uint_as_float(q.x << 16), a0);
        a1 = fmaf(v, __uint_as_float(q.x & 0xffff0000u), a1);
        a2 = fmaf(v, __uint_as_float(q.y << 16), a2);
        a3 = fmaf(v, __uint_as_float(q.y & 0xffff0000u), a3);
        a4 = fmaf(v, __uint_as_float(q.z << 16), a4);
        a5 = fmaf(v, __uint_as_float(q.z & 0xffff0000u), a5);
        a6 = fmaf(v, __uint_as_float(q.w << 16), a6);
        a7 = fmaf(v, __uint_as_float(q.w & 0xffff0000u), a7);
    }
    float4* tp = reinterpret_cast<float4*>(&tile[w][lane * 8]);
    tp[0] = make_float4(a0, a1, a2, a3);
    tp[1] = make_float4(a4, a5, a6, a7);
    __syncthreads();   // also publishes bias_l atomics

    // store: thread t -> b = t/4 (+256*k2), r-quad = (t%4)*4; float4 along r.
    // nt: written once, never re-read; full 64B lines per 4-thread group.
    const int rq = (threadIdx.x & 3) * 4;
    const float4 bv = make_float4(bias_l[rq + 0], bias_l[rq + 1],
                                  bias_l[rq + 2], bias_l[rq + 3]);
#pragma unroll
    for (int k2 = 0; k2 < 2; ++k2) {
        const int b = (threadIdx.x >> 2) + k2 * 256;
        f4 o = {tile[rq + 0][b] + bv.x, tile[rq + 1][b] + bv.y,
                tile[rq + 2][b] + bv.z, tile[rq + 3][b] + bv.w};
        __builtin_nontemporal_store(o, reinterpret_cast<f4*>(
            &out[(size_t)b * OUT_DIM + r0 + rq]));
    }
}

extern "C" void kernel_launch(void* const* d_in, const int* in_sizes, int n_in,
                              void* d_out, int out_size, void* d_ws, size_t ws_size,
                              hipStream_t stream) {
    const float* input   = (const float*)d_in[0];
    const int*   w_rows  = (const int*)d_in[1];
    const int*   w_cols  = (const int*)d_in[2];
    const float* w_vals  = (const float*)d_in[3];
    const int*   b_idx   = (const int*)d_in[4];
    const float* b_vals  = (const float*)d_in[5];
    float* out = (float*)d_out;

    char* ws = (char*)d_ws;
    const size_t MB = (size_t)1024 * 1024;
    unsigned short* inputT = (unsigned short*)ws;      // 4 MiB (bf16)
    int*   lrp   = (int*)(ws + 4 * MB);                // 64*4097*4 ~= 1.0 MiB
    int2*  slots = (int2*)(ws + 6 * MB);               // NNZ*8 = 2.56 MiB

    prep_k<<<NCHK + TT, 1024, 0, stream>>>(input, inputT, w_rows, w_cols, w_vals,
                                           lrp, slots);

    spmm_k<<<OUT_DIM / RT, 1024, 0, stream>>>(inputT, lrp, slots, b_idx, b_vals,
                                              out);
}